// Round 17
// baseline (108.267 us; speedup 1.0000x reference)
//
#include <hip/hip_runtime.h>

typedef __attribute__((ext_vector_type(8))) short short8;
typedef __attribute__((ext_vector_type(4))) float f32x4;

#define N_ROWS   65536
#define DIM      64
#define K_CODES  1024
#define TOTAL_ELEMS 4194304   // N_ROWS * DIM
#define THETA    1e-3f        // cert margin (proven passing r3-r16)
#define ROWS_PB  64           // rows per k_assign block (r5-proven shape)

// ---------------- ws layout (4-byte units) ----------------
// [0      , 1024 )   norms ||e_k||^2 (float)
// [1024   , 66560)   indices (int)
// [66560  , 67584)   counts (int)
// [67584  , 71680)   loss partials (float, 4096)
// [71680  , 137216)  cbT[k][d] f32
// [137216 , 169984)  cb_hi[k][d] bf16 of (-2*e)  (ushort)
// [169984 , 202752)  cb_lo[k][d] bf16 residual   (ushort)
// [202752]           flag counter (int)
// [202753 , 268289)  flag list (int)

__device__ __forceinline__ unsigned short f2bf(float f) {
    union { float f; unsigned int u; } c; c.f = f;
    unsigned int u = c.u;
    return (unsigned short)((u + 0x7fffu + ((u >> 16) & 1u)) >> 16);  // RNE
}
__device__ __forceinline__ float bf2f(unsigned short b) {
    union { unsigned int u; float f; } c; c.u = ((unsigned int)b) << 16;
    return c.f;
}
__device__ __forceinline__ f32x4 MFMA(short8 a, short8 b, f32x4 c) {
    return __builtin_amdgcn_mfma_f32_16x16x32_bf16(a, b, c, 0, 0, 0);
}

// Async-stage one 16-code chunk (2KB) of a bf16 codebook array into a
// wave-private LDS buffer via global_load_lds (lane-linear LDS dest, 16B/lane).
// Source is PRE-SWIZZLED (m173 pattern): physical chunk p holds logical chunk
// g(p) = (p&~7)|((p^(p>>3))&7)  (involution) so later ds_read_b128 fragment
// reads are bank-conflict-free.
__device__ __forceinline__ void stage_b(const unsigned short* __restrict__ cb,
                                        unsigned short* lds, int code16base, int lane) {
    const unsigned int* s = reinterpret_cast<const unsigned int*>(cb + (size_t)code16base * 64);
    unsigned int* l = reinterpret_cast<unsigned int*>(lds);
    int p0 = lane;
    int g0 = (p0 & ~7) | ((p0 ^ (p0 >> 3)) & 7);
    __builtin_amdgcn_global_load_lds(s + g0 * 4, l, 16, 0, 0);
    int p1 = 64 + lane;
    int g1 = (p1 & ~7) | ((p1 ^ (p1 >> 3)) & 7);
    __builtin_amdgcn_global_load_lds(s + g1 * 4, l + 256, 16, 0, 0);
}

// norms (sequential order — k_exact's reference emulation depends on it),
// cbT, bf16 split of -2*e; zero counts + flagcnt. (r12-proven, ~2us)
__global__ __launch_bounds__(64) void k_prep(const float* __restrict__ cb,
                                             float* __restrict__ norms,
                                             int* __restrict__ counts,
                                             float* __restrict__ cbT,
                                             unsigned short* __restrict__ cb_hi,
                                             unsigned short* __restrict__ cb_lo,
                                             int* __restrict__ flagcnt) {
    int k = blockIdx.x * 64 + threadIdx.x;   // 16 blocks -> 1024
    float v[64];
#pragma unroll
    for (int d = 0; d < DIM; ++d) v[d] = cb[d * K_CODES + k];   // coalesced, all in flight
    float s = __fmul_rn(v[0], v[0]);
#pragma unroll
    for (int d = 1; d < DIM; ++d) s = __fadd_rn(s, __fmul_rn(v[d], v[d]));  // bit-identical order
    norms[k] = s;
#pragma unroll
    for (int d = 0; d < DIM; ++d) {
        cbT[k * DIM + d] = v[d];
        float t = -2.0f * v[d];               // exact
        unsigned short hb = f2bf(t);
        cb_hi[k * DIM + d] = hb;
        cb_lo[k * DIM + d] = f2bf(t - bf2f(hb));
    }
    counts[k] = 0;
    if (k == 0) flagcnt[0] = 0;
}

// Phase 1: split-bf16 MFMA distance argmin with certificate.
// r16 body (59us, VGPR 88, no spill) + ONE change: merge scratch mv1/mv2/mk1
// aliased into bsh_hi (dead after last consume; one extra barrier for safety).
// LDS 56.6 -> 53.5 KB crosses the 3-blocks/CU threshold (+50% residency).
__global__ __launch_bounds__(256, 2) void k_assign(const float* __restrict__ x,
                                                   const float* __restrict__ norms,
                                                   const unsigned short* __restrict__ cb_hi,
                                                   const unsigned short* __restrict__ cb_lo,
                                                   int* __restrict__ idx_out,
                                                   int* __restrict__ flagcnt,
                                                   int* __restrict__ flaglist) {
    __shared__ __align__(16) unsigned short xs_hi[64 * 64];   // 8 KB, XOR-swizzled
    __shared__ __align__(16) unsigned short xs_lo[64 * 64];   // 8 KB
    __shared__ __align__(16) unsigned short bsh_hi[8 * 1024]; // 16 KB (B dbuf; epilogue: merge scratch)
    __shared__ __align__(16) unsigned short bsh_lo[8 * 1024]; // 16 KB
    __shared__ float nshf[1024];                              // 4 KB norms copy
    __shared__ float xxs[64];

    // merge scratch aliased into bsh_hi (B-buffers dead by then; barrier-protected)
    float* mv1 = reinterpret_cast<float*>(bsh_hi);            // [4][64]
    float* mv2 = mv1 + 256;                                   // [4][64]
    int*   mk1 = reinterpret_cast<int*>(mv2 + 256);           // [4][64]

    const int tid = threadIdx.x;
    const int r0 = blockIdx.x * 64;
    const int wave = tid >> 6, lane = tid & 63;
    const int lr = lane & 15, lg = lane >> 4;

    // ---- X staging (unchanged r5/r13) ----
#pragma unroll
    for (int i = 0; i < 2; ++i) {
        int c = i * 256 + tid;
        int row = c >> 3, ch = c & 7;
        const float4* src = reinterpret_cast<const float4*>(x + (size_t)(r0 + row) * DIM + ch * 8);
        float4 f0 = src[0], f1 = src[1];
        float f[8] = {f0.x, f0.y, f0.z, f0.w, f1.x, f1.y, f1.z, f1.w};
        union { short8 v; unsigned short u[8]; } h, l;
#pragma unroll
        for (int j = 0; j < 8; ++j) {
            unsigned short hb = f2bf(f[j]);
            h.u[j] = hb;
            l.u[j] = f2bf(f[j] - bf2f(hb));
        }
        int eo = row * 64 + ((((ch * 16) ^ ((row & 7) << 4))) >> 1);
        *reinterpret_cast<short8*>(&xs_hi[eo]) = h.v;
        *reinterpret_cast<short8*>(&xs_lo[eo]) = l.v;
    }
    if (lane < 16) {
        int row = wave * 16 + lane;
        const float* xr = x + (size_t)(r0 + row) * DIM;
        float r[8];
#pragma unroll
        for (int j = 0; j < 8; ++j) { float v = xr[j]; r[j] = __fmul_rn(v, v); }
#pragma unroll
        for (int m = 1; m < 8; ++m)
#pragma unroll
            for (int j = 0; j < 8; ++j) { float v = xr[8 * m + j]; r[j] = __fadd_rn(r[j], __fmul_rn(v, v)); }
        float t01 = __fadd_rn(r[0], r[1]), t23 = __fadd_rn(r[2], r[3]);
        float t45 = __fadd_rn(r[4], r[5]), t67 = __fadd_rn(r[6], r[7]);
        xxs[row] = __fadd_rn(__fadd_rn(t01, t23), __fadd_rn(t45, t67));
    }
    // norms -> LDS (wave-private consumption; off the vmcnt-counted path)
#pragma unroll
    for (int i = 0; i < 4; ++i) {
        int o = (wave << 8) + (i << 6) + lane;
        nshf[o] = norms[o];
    }
    __syncthreads();

    // ---- B double-buffer prologue: stage ct=0 and ct=1 (8 loads in flight) ----
    const int cbase = wave * 256;
    unsigned short* bh0 = bsh_hi + (wave * 2) * 1024;
    unsigned short* bh1 = bh0 + 1024;
    unsigned short* bl0 = bsh_lo + (wave * 2) * 1024;
    unsigned short* bl1 = bl0 + 1024;
    stage_b(cb_hi, bh0, cbase,      lane);
    stage_b(cb_lo, bl0, cbase,      lane);
    stage_b(cb_hi, bh1, cbase + 16, lane);
    stage_b(cb_lo, bl1, cbase + 16, lane);

    // ---- A-frags (unchanged) ----
    short8 a_hi[4][2], a_lo[4][2];
#pragma unroll
    for (int rt = 0; rt < 4; ++rt)
#pragma unroll
        for (int kh = 0; kh < 2; ++kh) {
            int row = rt * 16 + lr;
            int bo = (kh * 64 + lg * 16) ^ ((row & 7) << 4);
            int eo = row * 64 + (bo >> 1);
            a_hi[rt][kh] = *reinterpret_cast<const short8*>(&xs_hi[eo]);
            a_lo[rt][kh] = *reinterpret_cast<const short8*>(&xs_lo[eo]);
        }
    float xxv[16];
#pragma unroll
    for (int rt = 0; rt < 4; ++rt)
#pragma unroll
        for (int r = 0; r < 4; ++r) xxv[rt * 4 + r] = xxs[rt * 16 + lg * 4 + r];

    float v1[16], v2[16]; int k1[16];
#pragma unroll
    for (int i = 0; i < 16; ++i) { v1[i] = 3.4e38f; v2[i] = 3.4e38f; k1[i] = 0; }

    // fragment LDS indices (ushort units): physical chunk = lr*8 + (s ^ (lr&7))
    const int pc0 = (((lr << 3) + ((lg)     ^ (lr & 7))) << 3);  // kh=0
    const int pc1 = (((lr << 3) + ((4 + lg) ^ (lr & 7))) << 3);  // kh=1

    auto consume = [&](int ct_, const unsigned short* bh, const unsigned short* bl) {
        float ee = nshf[(wave << 8) + (ct_ << 4) + lr];
        short8 h0 = *reinterpret_cast<const short8*>(bh + pc0);
        short8 h1 = *reinterpret_cast<const short8*>(bh + pc1);
        short8 l0 = *reinterpret_cast<const short8*>(bl + pc0);
        short8 l1 = *reinterpret_cast<const short8*>(bl + pc1);
        int code = cbase + (ct_ << 4) + lr;   // ascending per lane: lowest-k on tie
#pragma unroll
        for (int rt = 0; rt < 4; ++rt) {
            f32x4 acc;
            acc[0] = __fadd_rn(xxv[rt * 4 + 0], ee);
            acc[1] = __fadd_rn(xxv[rt * 4 + 1], ee);
            acc[2] = __fadd_rn(xxv[rt * 4 + 2], ee);
            acc[3] = __fadd_rn(xxv[rt * 4 + 3], ee);
            __builtin_amdgcn_s_setprio(1);
            acc = MFMA(a_hi[rt][0], h0, acc);
            acc = MFMA(a_hi[rt][1], h1, acc);
            acc = MFMA(a_hi[rt][0], l0, acc);
            acc = MFMA(a_hi[rt][1], l1, acc);
            acc = MFMA(a_lo[rt][0], h0, acc);
            acc = MFMA(a_lo[rt][1], h1, acc);
            __builtin_amdgcn_s_setprio(0);
#pragma unroll
            for (int r = 0; r < 4; ++r) {
                int i = rt * 4 + r;
                float d = acc[r];
                v2[i] = __builtin_amdgcn_fmed3f(d, v1[i], v2[i]);  // exact new 2nd-min
                bool lt = d < v1[i];
                k1[i] = lt ? code : k1[i];
                v1[i] = fminf(v1[i], d);
            }
        }
    };

    // Main loop: counted waits. Entering iter ct: outstanding = S_ct + S_{ct+1}
    // (8 loads). vmcnt(4) waits exactly for S_ct (in-order retirement).
    for (int ct = 0; ct < 14; ++ct) {
        asm volatile("s_waitcnt vmcnt(4)" ::: "memory");
        unsigned short* bh = (ct & 1) ? bh1 : bh0;
        unsigned short* bl = (ct & 1) ? bl1 : bl0;
        consume(ct, bh, bl);
        asm volatile("s_waitcnt lgkmcnt(0)" ::: "memory");   // frag reads done before overwrite
        __builtin_amdgcn_sched_barrier(0);
        stage_b(cb_hi, bh, cbase + (ct + 2) * 16, lane);
        stage_b(cb_lo, bl, cbase + (ct + 2) * 16, lane);
    }
    asm volatile("s_waitcnt vmcnt(4)" ::: "memory");   // S14 landed (S15 may fly)
    consume(14, bh0, bl0);
    asm volatile("s_waitcnt vmcnt(0)" ::: "memory");   // drain S15
    consume(15, bh1, bl1);

    // All waves done consuming B-buffers before any wave overwrites them with
    // merge scratch (mv* aliases bsh_hi).
    __syncthreads();

    // ---- epilogue (r13 logic; mv* aliased) ----
#pragma unroll
    for (int i = 0; i < 16; ++i) {
        float a1 = v1[i], a2 = v2[i]; int ak = k1[i];
#pragma unroll
        for (int off = 1; off <= 8; off <<= 1) {
            float o1 = __shfl_xor(a1, off);
            float o2 = __shfl_xor(a2, off);
            int   ok = __shfl_xor(ak, off);
            float n2 = fminf(fmaxf(a1, o1), fminf(a2, o2));
            if (o1 < a1 || (o1 == a1 && ok < ak)) { a1 = o1; ak = ok; }
            a2 = n2;
        }
        if (lr == 0) {
            int row = (i >> 2) * 16 + lg * 4 + (i & 3);
            mv1[wave * 64 + row] = a1; mv2[wave * 64 + row] = a2; mk1[wave * 64 + row] = ak;
        }
    }
    __syncthreads();

    if (tid < 64) {
        float V1 = mv1[tid], V2 = mv2[tid]; int K1 = mk1[tid];
#pragma unroll
        for (int w = 1; w < 4; ++w) {
            float a1 = mv1[w * 64 + tid], a2 = mv2[w * 64 + tid]; int ak = mk1[w * 64 + tid];
            float n2 = fminf(fmaxf(V1, a1), fminf(V2, a2));
            if (a1 < V1) { V1 = a1; K1 = ak; }
            V2 = n2;
        }
        int rg = r0 + tid;
        idx_out[rg] = K1;                      // placeholder if flagged
        if (V2 - V1 <= THETA) {
            int p = atomicAdd(flagcnt, 1);     // set deterministic; order irrelevant
            flaglist[p] = rg;
        }
    }
}

// Phase 2: exact re-rank. 8 flagged rows per group, coalesced d-major
// codebook reads amortized over the 8 rows; grid-stride over groups.
__global__ __launch_bounds__(256) void k_exact(const float* __restrict__ x,
                                               const float* __restrict__ cb,
                                               const float* __restrict__ norms,
                                               const int* __restrict__ flagcnt,
                                               const int* __restrict__ flaglist,
                                               int* __restrict__ idx) {
    __shared__ __align__(16) float xrow[8][64];
    __shared__ float xxs[8];
    __shared__ int rlist[8];
    __shared__ float lv[8][4];
    __shared__ int   lk[8][4];

    const int tid = threadIdx.x;
    const int lane = tid & 63, wv = tid >> 6;
    const int cnt = flagcnt[0];
    const int ngroups = (cnt + 7) >> 3;

    for (int g = blockIdx.x; g < ngroups; g += gridDim.x) {
        const int base = g * 8;
        const int rem = min(8, cnt - base);
        __syncthreads();                        // protect LDS reuse across groups
        if (tid < 8)
            rlist[tid] = flaglist[base + ((tid < rem) ? tid : 0)];
        __syncthreads();
#pragma unroll
        for (int i = 0; i < 2; ++i) {           // 512 elements
            int e = i * 256 + tid;
            int r = e >> 6, d = e & 63;
            xrow[r][d] = x[(size_t)rlist[r] * DIM + d];
        }
        __syncthreads();
        if (tid < 8) {                          // numpy pairwise ||x||^2
            float rr[8];
#pragma unroll
            for (int j = 0; j < 8; ++j) { float v = xrow[tid][j]; rr[j] = __fmul_rn(v, v); }
#pragma unroll
            for (int m = 1; m < 8; ++m)
#pragma unroll
                for (int j = 0; j < 8; ++j) { float v = xrow[tid][8 * m + j]; rr[j] = __fadd_rn(rr[j], __fmul_rn(v, v)); }
            float t01 = __fadd_rn(rr[0], rr[1]), t23 = __fadd_rn(rr[2], rr[3]);
            float t45 = __fadd_rn(rr[4], rr[5]), t67 = __fadd_rn(rr[6], rr[7]);
            xxs[tid] = __fadd_rn(__fadd_rn(t01, t23), __fadd_rn(t45, t67));
        }
        __syncthreads();

        double acc[8][4];
#pragma unroll
        for (int r = 0; r < 8; ++r)
#pragma unroll
            for (int j = 0; j < 4; ++j) acc[r][j] = 0.0;

        for (int dc = 0; dc < DIM; dc += 4) {
            float4 xv[8];
#pragma unroll
            for (int r = 0; r < 8; ++r)
                xv[r] = *reinterpret_cast<const float4*>(&xrow[r][dc]);   // LDS broadcast
            float c[4][4];
#pragma unroll
            for (int dd = 0; dd < 4; ++dd)
#pragma unroll
                for (int j = 0; j < 4; ++j)
                    c[j][dd] = cb[(size_t)(dc + dd) * K_CODES + j * 256 + tid];  // coalesced
#pragma unroll
            for (int j = 0; j < 4; ++j)
#pragma unroll
                for (int r = 0; r < 8; ++r) {
                    acc[r][j] += (double)xv[r].x * (double)c[j][0];
                    acc[r][j] += (double)xv[r].y * (double)c[j][1];
                    acc[r][j] += (double)xv[r].z * (double)c[j][2];
                    acc[r][j] += (double)xv[r].w * (double)c[j][3];
                }
        }

#pragma unroll
        for (int r = 0; r < 8; ++r) {
            float xx = xxs[r];
            float bv = 3.4e38f; int bk = 0x7fffffff;
#pragma unroll
            for (int j = 0; j < 4; ++j) {       // ascending k per thread
                int k = j * 256 + tid;
                float m = (float)acc[r][j];
                float dist = __fsub_rn(__fadd_rn(xx, norms[k]), __fmul_rn(2.0f, m));
                if (dist < bv) { bv = dist; bk = k; }
            }
#pragma unroll
            for (int off = 1; off <= 32; off <<= 1) {
                float ov = __shfl_xor(bv, off); int ok = __shfl_xor(bk, off);
                if (ov < bv || (ov == bv && ok < bk)) { bv = ov; bk = ok; }
            }
            if (lane == 0) { lv[r][wv] = bv; lk[r][wv] = bk; }
        }
        __syncthreads();
        if (tid < rem) {
            float bv = lv[tid][0]; int bk = lk[tid][0];
#pragma unroll
            for (int w = 1; w < 4; ++w)
                if (lv[tid][w] < bv || (lv[tid][w] == bv && lk[tid][w] < bk)) { bv = lv[tid][w]; bk = lk[tid][w]; }
            idx[rlist[tid]] = bk;
        }
    }
}

// Gather + STE + loss partial + fused histogram + idxf write.
__global__ __launch_bounds__(256) void k_quant(const float* __restrict__ x,
                                               const float* __restrict__ cbT,
                                               const int* __restrict__ idx,
                                               float* __restrict__ ste,
                                               float* __restrict__ partials,
                                               int* __restrict__ counts,
                                               float* __restrict__ idxf) {
    int t  = blockIdx.x * 256 + threadIdx.x;
    int e  = t << 2;
    int n  = e >> 6;
    int dc = e & 63;
    float4 xv = *reinterpret_cast<const float4*>(x + e);
    int k = idx[n];
    float4 qv = *reinterpret_cast<const float4*>(cbT + (size_t)k * DIM + dc);

    float4 sv;
    sv.x = xv.x + (qv.x - xv.x);
    sv.y = xv.y + (qv.y - xv.y);
    sv.z = xv.z + (qv.z - xv.z);
    sv.w = xv.w + (qv.w - xv.w);
    *reinterpret_cast<float4*>(ste + e) = sv;

    if (dc == 0) {
        atomicAdd(&counts[k], 1);
        idxf[n] = (float)k;
    }

    float dx = qv.x - xv.x, dy = qv.y - xv.y, dz = qv.z - xv.z, dw = qv.w - xv.w;
    float s = dx * dx + dy * dy + dz * dz + dw * dw;

#pragma unroll
    for (int off = 32; off >= 1; off >>= 1) s += __shfl_down(s, off);
    __shared__ float red[4];
    int wave = threadIdx.x >> 6, lane = threadIdx.x & 63;
    if (lane == 0) red[wave] = s;
    __syncthreads();
    if (threadIdx.x == 0)
        partials[blockIdx.x] = (red[0] + red[1]) + (red[2] + red[3]);
}

__global__ __launch_bounds__(1024) void k_final(const float* __restrict__ partials,
                                                const int* __restrict__ counts,
                                                float* __restrict__ out_scalars) {
    int tid = threadIdx.x;
    float s = 0.f;
    for (int i = tid; i < 4096; i += 1024) s += partials[i];
#pragma unroll
    for (int off = 32; off >= 1; off >>= 1) s += __shfl_down(s, off);
    __shared__ float wsum[16];
    int wave = tid >> 6, lane = tid & 63;
    if (lane == 0) wsum[wave] = s;

    float c = (float)counts[tid];
    float p = c * (1.0f / 65536.0f);
    float t = -p * logf(p + 1e-10f);
#pragma unroll
    for (int off = 32; off >= 1; off >>= 1) t += __shfl_down(t, off);
    __shared__ float esum[16];
    if (lane == 0) esum[wave] = t;
    __syncthreads();

    if (tid == 0) {
        float total = 0.f, ent = 0.f;
        for (int w = 0; w < 16; ++w) { total += wsum[w]; ent += esum[w]; }
        float mean = total * (1.0f / (float)TOTAL_ELEMS);
        out_scalars[0] = expf(ent);
        out_scalars[1] = mean;
        out_scalars[2] = 0.25f * mean;
    }
}

extern "C" void kernel_launch(void* const* d_in, const int* in_sizes, int n_in,
                              void* d_out, int out_size, void* d_ws, size_t ws_size,
                              hipStream_t stream) {
    const float* x  = (const float*)d_in[0];
    const float* cb = (const float*)d_in[1];
    float* out = (float*)d_out;
    float* ws  = (float*)d_ws;

    float* norms    = ws;
    int*   idx      = (int*)(ws + 1024);
    int*   counts   = (int*)(ws + 66560);
    float* partials = ws + 67584;
    float* cbT      = ws + 71680;
    unsigned short* cb_hi = (unsigned short*)(ws + 137216);
    unsigned short* cb_lo = (unsigned short*)(ws + 169984);
    int*   flagcnt  = (int*)(ws + 202752);
    int*   flaglist = (int*)(ws + 202753);

    float* ste     = out;
    float* scalars = out + TOTAL_ELEMS;
    float* idxf    = out + TOTAL_ELEMS + 3;

    k_prep  <<<16,    64, 0, stream>>>(cb, norms, counts, cbT, cb_hi, cb_lo, flagcnt);
    k_assign<<<1024, 256, 0, stream>>>(x, norms, cb_hi, cb_lo, idx, flagcnt, flaglist);
    k_exact <<<1024, 256, 0, stream>>>(x, cb, norms, flagcnt, flaglist, idx);
    k_quant <<<4096, 256, 0, stream>>>(x, cbT, idx, ste, partials, counts, idxf);
    k_final <<<1,   1024, 0, stream>>>(partials, counts, scalars);
}

// Round 18
// 108.134 us; speedup vs baseline: 1.0012x; 1.0012x over previous
//
#include <hip/hip_runtime.h>

typedef __attribute__((ext_vector_type(8))) short short8;
typedef __attribute__((ext_vector_type(4))) float f32x4;

#define N_ROWS   65536
#define DIM      64
#define K_CODES  1024
#define TOTAL_ELEMS 4194304   // N_ROWS * DIM
#define THETA    1e-3f        // cert margin (proven passing r3-r17)
#define ROWS_PB  64           // rows per k_assign block (r5-proven shape)

// ---------------- ws layout (4-byte units) ----------------
// [0      , 1024 )   norms ||e_k||^2 (float)
// [1024   , 66560)   indices (int)
// [66560  , 67584)   counts (int)
// [67584  , 71680)   loss partials (float, 4096)
// [71680  , 137216)  cbT[k][d] f32
// [137216 , 169984)  cb_hi[k][d] bf16 of (-2*e)  (ushort)
// [169984 , 202752)  cb_lo[k][d] bf16 residual   (ushort)
// [202752]           flag counter (int)
// [202753 , 268289)  flag list (int)

__device__ __forceinline__ unsigned short f2bf(float f) {
    union { float f; unsigned int u; } c; c.f = f;
    unsigned int u = c.u;
    return (unsigned short)((u + 0x7fffu + ((u >> 16) & 1u)) >> 16);  // RNE
}
__device__ __forceinline__ float bf2f(unsigned short b) {
    union { unsigned int u; float f; } c; c.u = ((unsigned int)b) << 16;
    return c.f;
}
__device__ __forceinline__ f32x4 MFMA(short8 a, short8 b, f32x4 c) {
    return __builtin_amdgcn_mfma_f32_16x16x32_bf16(a, b, c, 0, 0, 0);
}

// Async-stage one 16-code chunk (2KB) of a bf16 codebook array into a
// wave-private LDS buffer via global_load_lds (lane-linear LDS dest, 16B/lane).
// Source is PRE-SWIZZLED (m173 pattern): physical chunk p holds logical chunk
// g(p) = (p&~7)|((p^(p>>3))&7)  (involution) so ds_read_b128 fragment reads
// are bank-conflict-free.
__device__ __forceinline__ void stage_b(const unsigned short* __restrict__ cb,
                                        unsigned short* lds, int code16base, int lane) {
    const unsigned int* s = reinterpret_cast<const unsigned int*>(cb + (size_t)code16base * 64);
    unsigned int* l = reinterpret_cast<unsigned int*>(lds);
    int p0 = lane;
    int g0 = (p0 & ~7) | ((p0 ^ (p0 >> 3)) & 7);
    __builtin_amdgcn_global_load_lds(s + g0 * 4, l, 16, 0, 0);
    int p1 = 64 + lane;
    int g1 = (p1 & ~7) | ((p1 ^ (p1 >> 3)) & 7);
    __builtin_amdgcn_global_load_lds(s + g1 * 4, l + 256, 16, 0, 0);
}

// norms (sequential order — k_exact's reference emulation depends on it),
// cbT, bf16 split of -2*e; zero counts + flagcnt. (r12-proven, ~2us)
__global__ __launch_bounds__(64) void k_prep(const float* __restrict__ cb,
                                             float* __restrict__ norms,
                                             int* __restrict__ counts,
                                             float* __restrict__ cbT,
                                             unsigned short* __restrict__ cb_hi,
                                             unsigned short* __restrict__ cb_lo,
                                             int* __restrict__ flagcnt) {
    int k = blockIdx.x * 64 + threadIdx.x;   // 16 blocks -> 1024
    float v[64];
#pragma unroll
    for (int d = 0; d < DIM; ++d) v[d] = cb[d * K_CODES + k];   // coalesced, all in flight
    float s = __fmul_rn(v[0], v[0]);
#pragma unroll
    for (int d = 1; d < DIM; ++d) s = __fadd_rn(s, __fmul_rn(v[d], v[d]));  // bit-identical order
    norms[k] = s;
#pragma unroll
    for (int d = 0; d < DIM; ++d) {
        cbT[k * DIM + d] = v[d];
        float t = -2.0f * v[d];               // exact
        unsigned short hb = f2bf(t);
        cb_hi[k * DIM + d] = hb;
        cb_lo[k * DIM + d] = f2bf(t - bf2f(hb));
    }
    counts[k] = 0;
    if (k == 0) flagcnt[0] = 0;
}

// Phase 1: split-bf16 MFMA distance argmin with certificate.
// r17 body (59us, VGPR 88, no spill) + ONE change: each rt's 6-MFMA serial
// chain split into two 3-deep chains (accA: kh=0 terms init xx+ee; accB:
// kh=1 terms init 0; d = accA+accB). 8 independent MFMA chains per ct
// instead of 4 — doubles ILP against MFMA result latency. Summation-order
// delta ~1e-6 << THETA. Tripwire: VGPR>=128 / WRITE~100MB => revert r16.
__global__ __launch_bounds__(256, 2) void k_assign(const float* __restrict__ x,
                                                   const float* __restrict__ norms,
                                                   const unsigned short* __restrict__ cb_hi,
                                                   const unsigned short* __restrict__ cb_lo,
                                                   int* __restrict__ idx_out,
                                                   int* __restrict__ flagcnt,
                                                   int* __restrict__ flaglist) {
    __shared__ __align__(16) unsigned short xs_hi[64 * 64];   // 8 KB, XOR-swizzled
    __shared__ __align__(16) unsigned short xs_lo[64 * 64];   // 8 KB
    __shared__ __align__(16) unsigned short bsh_hi[8 * 1024]; // 16 KB (B dbuf; epilogue: merge scratch)
    __shared__ __align__(16) unsigned short bsh_lo[8 * 1024]; // 16 KB
    __shared__ float nshf[1024];                              // 4 KB norms copy
    __shared__ float xxs[64];

    // merge scratch aliased into bsh_hi (B-buffers dead by then; barrier-protected)
    float* mv1 = reinterpret_cast<float*>(bsh_hi);            // [4][64]
    float* mv2 = mv1 + 256;                                   // [4][64]
    int*   mk1 = reinterpret_cast<int*>(mv2 + 256);           // [4][64]

    const int tid = threadIdx.x;
    const int r0 = blockIdx.x * 64;
    const int wave = tid >> 6, lane = tid & 63;
    const int lr = lane & 15, lg = lane >> 4;

    // ---- X staging (unchanged r5/r13) ----
#pragma unroll
    for (int i = 0; i < 2; ++i) {
        int c = i * 256 + tid;
        int row = c >> 3, ch = c & 7;
        const float4* src = reinterpret_cast<const float4*>(x + (size_t)(r0 + row) * DIM + ch * 8);
        float4 f0 = src[0], f1 = src[1];
        float f[8] = {f0.x, f0.y, f0.z, f0.w, f1.x, f1.y, f1.z, f1.w};
        union { short8 v; unsigned short u[8]; } h, l;
#pragma unroll
        for (int j = 0; j < 8; ++j) {
            unsigned short hb = f2bf(f[j]);
            h.u[j] = hb;
            l.u[j] = f2bf(f[j] - bf2f(hb));
        }
        int eo = row * 64 + ((((ch * 16) ^ ((row & 7) << 4))) >> 1);
        *reinterpret_cast<short8*>(&xs_hi[eo]) = h.v;
        *reinterpret_cast<short8*>(&xs_lo[eo]) = l.v;
    }
    if (lane < 16) {
        int row = wave * 16 + lane;
        const float* xr = x + (size_t)(r0 + row) * DIM;
        float r[8];
#pragma unroll
        for (int j = 0; j < 8; ++j) { float v = xr[j]; r[j] = __fmul_rn(v, v); }
#pragma unroll
        for (int m = 1; m < 8; ++m)
#pragma unroll
            for (int j = 0; j < 8; ++j) { float v = xr[8 * m + j]; r[j] = __fadd_rn(r[j], __fmul_rn(v, v)); }
        float t01 = __fadd_rn(r[0], r[1]), t23 = __fadd_rn(r[2], r[3]);
        float t45 = __fadd_rn(r[4], r[5]), t67 = __fadd_rn(r[6], r[7]);
        xxs[row] = __fadd_rn(__fadd_rn(t01, t23), __fadd_rn(t45, t67));
    }
    // norms -> LDS (wave-private consumption; off the vmcnt-counted path)
#pragma unroll
    for (int i = 0; i < 4; ++i) {
        int o = (wave << 8) + (i << 6) + lane;
        nshf[o] = norms[o];
    }
    __syncthreads();

    // ---- B double-buffer prologue: stage ct=0 and ct=1 (8 loads in flight) ----
    const int cbase = wave * 256;
    unsigned short* bh0 = bsh_hi + (wave * 2) * 1024;
    unsigned short* bh1 = bh0 + 1024;
    unsigned short* bl0 = bsh_lo + (wave * 2) * 1024;
    unsigned short* bl1 = bl0 + 1024;
    stage_b(cb_hi, bh0, cbase,      lane);
    stage_b(cb_lo, bl0, cbase,      lane);
    stage_b(cb_hi, bh1, cbase + 16, lane);
    stage_b(cb_lo, bl1, cbase + 16, lane);

    // ---- A-frags (unchanged) ----
    short8 a_hi[4][2], a_lo[4][2];
#pragma unroll
    for (int rt = 0; rt < 4; ++rt)
#pragma unroll
        for (int kh = 0; kh < 2; ++kh) {
            int row = rt * 16 + lr;
            int bo = (kh * 64 + lg * 16) ^ ((row & 7) << 4);
            int eo = row * 64 + (bo >> 1);
            a_hi[rt][kh] = *reinterpret_cast<const short8*>(&xs_hi[eo]);
            a_lo[rt][kh] = *reinterpret_cast<const short8*>(&xs_lo[eo]);
        }
    float xxv[16];
#pragma unroll
    for (int rt = 0; rt < 4; ++rt)
#pragma unroll
        for (int r = 0; r < 4; ++r) xxv[rt * 4 + r] = xxs[rt * 16 + lg * 4 + r];

    float v1[16], v2[16]; int k1[16];
#pragma unroll
    for (int i = 0; i < 16; ++i) { v1[i] = 3.4e38f; v2[i] = 3.4e38f; k1[i] = 0; }

    // fragment LDS indices (ushort units): physical chunk = lr*8 + (s ^ (lr&7))
    const int pc0 = (((lr << 3) + ((lg)     ^ (lr & 7))) << 3);  // kh=0
    const int pc1 = (((lr << 3) + ((4 + lg) ^ (lr & 7))) << 3);  // kh=1

    auto consume = [&](int ct_, const unsigned short* bh, const unsigned short* bl) {
        float ee = nshf[(wave << 8) + (ct_ << 4) + lr];
        short8 h0 = *reinterpret_cast<const short8*>(bh + pc0);
        short8 h1 = *reinterpret_cast<const short8*>(bh + pc1);
        short8 l0 = *reinterpret_cast<const short8*>(bl + pc0);
        short8 l1 = *reinterpret_cast<const short8*>(bl + pc1);
        int code = cbase + (ct_ << 4) + lr;   // ascending per lane: lowest-k on tie
#pragma unroll
        for (int rt = 0; rt < 4; ++rt) {
            f32x4 accA, accB;
            accA[0] = __fadd_rn(xxv[rt * 4 + 0], ee);
            accA[1] = __fadd_rn(xxv[rt * 4 + 1], ee);
            accA[2] = __fadd_rn(xxv[rt * 4 + 2], ee);
            accA[3] = __fadd_rn(xxv[rt * 4 + 3], ee);
            accB[0] = 0.f; accB[1] = 0.f; accB[2] = 0.f; accB[3] = 0.f;
            __builtin_amdgcn_s_setprio(1);
            accA = MFMA(a_hi[rt][0], h0, accA);   // two independent 3-deep chains
            accB = MFMA(a_hi[rt][1], h1, accB);
            accA = MFMA(a_hi[rt][0], l0, accA);
            accB = MFMA(a_hi[rt][1], l1, accB);
            accA = MFMA(a_lo[rt][0], h0, accA);
            accB = MFMA(a_lo[rt][1], h1, accB);
            __builtin_amdgcn_s_setprio(0);
#pragma unroll
            for (int r = 0; r < 4; ++r) {
                int i = rt * 4 + r;
                float d = __fadd_rn(accA[r], accB[r]);
                v2[i] = __builtin_amdgcn_fmed3f(d, v1[i], v2[i]);  // exact new 2nd-min
                bool lt = d < v1[i];
                k1[i] = lt ? code : k1[i];
                v1[i] = fminf(v1[i], d);
            }
        }
    };

    // Main loop: counted waits. Entering iter ct: outstanding = S_ct + S_{ct+1}
    // (8 loads). vmcnt(4) waits exactly for S_ct (in-order retirement).
    for (int ct = 0; ct < 14; ++ct) {
        asm volatile("s_waitcnt vmcnt(4)" ::: "memory");
        unsigned short* bh = (ct & 1) ? bh1 : bh0;
        unsigned short* bl = (ct & 1) ? bl1 : bl0;
        consume(ct, bh, bl);
        asm volatile("s_waitcnt lgkmcnt(0)" ::: "memory");   // frag reads done before overwrite
        __builtin_amdgcn_sched_barrier(0);
        stage_b(cb_hi, bh, cbase + (ct + 2) * 16, lane);
        stage_b(cb_lo, bl, cbase + (ct + 2) * 16, lane);
    }
    asm volatile("s_waitcnt vmcnt(4)" ::: "memory");   // S14 landed (S15 may fly)
    consume(14, bh0, bl0);
    asm volatile("s_waitcnt vmcnt(0)" ::: "memory");   // drain S15
    consume(15, bh1, bl1);

    // All waves done consuming B-buffers before any wave overwrites them with
    // merge scratch (mv* aliases bsh_hi).
    __syncthreads();

    // ---- epilogue (r13 logic; mv* aliased) ----
#pragma unroll
    for (int i = 0; i < 16; ++i) {
        float a1 = v1[i], a2 = v2[i]; int ak = k1[i];
#pragma unroll
        for (int off = 1; off <= 8; off <<= 1) {
            float o1 = __shfl_xor(a1, off);
            float o2 = __shfl_xor(a2, off);
            int   ok = __shfl_xor(ak, off);
            float n2 = fminf(fmaxf(a1, o1), fminf(a2, o2));
            if (o1 < a1 || (o1 == a1 && ok < ak)) { a1 = o1; ak = ok; }
            a2 = n2;
        }
        if (lr == 0) {
            int row = (i >> 2) * 16 + lg * 4 + (i & 3);
            mv1[wave * 64 + row] = a1; mv2[wave * 64 + row] = a2; mk1[wave * 64 + row] = ak;
        }
    }
    __syncthreads();

    if (tid < 64) {
        float V1 = mv1[tid], V2 = mv2[tid]; int K1 = mk1[tid];
#pragma unroll
        for (int w = 1; w < 4; ++w) {
            float a1 = mv1[w * 64 + tid], a2 = mv2[w * 64 + tid]; int ak = mk1[w * 64 + tid];
            float n2 = fminf(fmaxf(V1, a1), fminf(V2, a2));
            if (a1 < V1) { V1 = a1; K1 = ak; }
            V2 = n2;
        }
        int rg = r0 + tid;
        idx_out[rg] = K1;                      // placeholder if flagged
        if (V2 - V1 <= THETA) {
            int p = atomicAdd(flagcnt, 1);     // set deterministic; order irrelevant
            flaglist[p] = rg;
        }
    }
}

// Phase 2: exact re-rank. 8 flagged rows per group, coalesced d-major
// codebook reads amortized over the 8 rows; grid-stride over groups.
__global__ __launch_bounds__(256) void k_exact(const float* __restrict__ x,
                                               const float* __restrict__ cb,
                                               const float* __restrict__ norms,
                                               const int* __restrict__ flagcnt,
                                               const int* __restrict__ flaglist,
                                               int* __restrict__ idx) {
    __shared__ __align__(16) float xrow[8][64];
    __shared__ float xxs[8];
    __shared__ int rlist[8];
    __shared__ float lv[8][4];
    __shared__ int   lk[8][4];

    const int tid = threadIdx.x;
    const int lane = tid & 63, wv = tid >> 6;
    const int cnt = flagcnt[0];
    const int ngroups = (cnt + 7) >> 3;

    for (int g = blockIdx.x; g < ngroups; g += gridDim.x) {
        const int base = g * 8;
        const int rem = min(8, cnt - base);
        __syncthreads();                        // protect LDS reuse across groups
        if (tid < 8)
            rlist[tid] = flaglist[base + ((tid < rem) ? tid : 0)];
        __syncthreads();
#pragma unroll
        for (int i = 0; i < 2; ++i) {           // 512 elements
            int e = i * 256 + tid;
            int r = e >> 6, d = e & 63;
            xrow[r][d] = x[(size_t)rlist[r] * DIM + d];
        }
        __syncthreads();
        if (tid < 8) {                          // numpy pairwise ||x||^2
            float rr[8];
#pragma unroll
            for (int j = 0; j < 8; ++j) { float v = xrow[tid][j]; rr[j] = __fmul_rn(v, v); }
#pragma unroll
            for (int m = 1; m < 8; ++m)
#pragma unroll
                for (int j = 0; j < 8; ++j) { float v = xrow[tid][8 * m + j]; rr[j] = __fadd_rn(rr[j], __fmul_rn(v, v)); }
            float t01 = __fadd_rn(rr[0], rr[1]), t23 = __fadd_rn(rr[2], rr[3]);
            float t45 = __fadd_rn(rr[4], rr[5]), t67 = __fadd_rn(rr[6], rr[7]);
            xxs[tid] = __fadd_rn(__fadd_rn(t01, t23), __fadd_rn(t45, t67));
        }
        __syncthreads();

        double acc[8][4];
#pragma unroll
        for (int r = 0; r < 8; ++r)
#pragma unroll
            for (int j = 0; j < 4; ++j) acc[r][j] = 0.0;

        for (int dc = 0; dc < DIM; dc += 4) {
            float4 xv[8];
#pragma unroll
            for (int r = 0; r < 8; ++r)
                xv[r] = *reinterpret_cast<const float4*>(&xrow[r][dc]);   // LDS broadcast
            float c[4][4];
#pragma unroll
            for (int dd = 0; dd < 4; ++dd)
#pragma unroll
                for (int j = 0; j < 4; ++j)
                    c[j][dd] = cb[(size_t)(dc + dd) * K_CODES + j * 256 + tid];  // coalesced
#pragma unroll
            for (int j = 0; j < 4; ++j)
#pragma unroll
                for (int r = 0; r < 8; ++r) {
                    acc[r][j] += (double)xv[r].x * (double)c[j][0];
                    acc[r][j] += (double)xv[r].y * (double)c[j][1];
                    acc[r][j] += (double)xv[r].z * (double)c[j][2];
                    acc[r][j] += (double)xv[r].w * (double)c[j][3];
                }
        }

#pragma unroll
        for (int r = 0; r < 8; ++r) {
            float xx = xxs[r];
            float bv = 3.4e38f; int bk = 0x7fffffff;
#pragma unroll
            for (int j = 0; j < 4; ++j) {       // ascending k per thread
                int k = j * 256 + tid;
                float m = (float)acc[r][j];
                float dist = __fsub_rn(__fadd_rn(xx, norms[k]), __fmul_rn(2.0f, m));
                if (dist < bv) { bv = dist; bk = k; }
            }
#pragma unroll
            for (int off = 1; off <= 32; off <<= 1) {
                float ov = __shfl_xor(bv, off); int ok = __shfl_xor(bk, off);
                if (ov < bv || (ov == bv && ok < bk)) { bv = ov; bk = ok; }
            }
            if (lane == 0) { lv[r][wv] = bv; lk[r][wv] = bk; }
        }
        __syncthreads();
        if (tid < rem) {
            float bv = lv[tid][0]; int bk = lk[tid][0];
#pragma unroll
            for (int w = 1; w < 4; ++w)
                if (lv[tid][w] < bv || (lv[tid][w] == bv && lk[tid][w] < bk)) { bv = lv[tid][w]; bk = lk[tid][w]; }
            idx[rlist[tid]] = bk;
        }
    }
}

// Gather + STE + loss partial + fused histogram + idxf write.
__global__ __launch_bounds__(256) void k_quant(const float* __restrict__ x,
                                               const float* __restrict__ cbT,
                                               const int* __restrict__ idx,
                                               float* __restrict__ ste,
                                               float* __restrict__ partials,
                                               int* __restrict__ counts,
                                               float* __restrict__ idxf) {
    int t  = blockIdx.x * 256 + threadIdx.x;
    int e  = t << 2;
    int n  = e >> 6;
    int dc = e & 63;
    float4 xv = *reinterpret_cast<const float4*>(x + e);
    int k = idx[n];
    float4 qv = *reinterpret_cast<const float4*>(cbT + (size_t)k * DIM + dc);

    float4 sv;
    sv.x = xv.x + (qv.x - xv.x);
    sv.y = xv.y + (qv.y - xv.y);
    sv.z = xv.z + (qv.z - xv.z);
    sv.w = xv.w + (qv.w - xv.w);
    *reinterpret_cast<float4*>(ste + e) = sv;

    if (dc == 0) {
        atomicAdd(&counts[k], 1);
        idxf[n] = (float)k;
    }

    float dx = qv.x - xv.x, dy = qv.y - xv.y, dz = qv.z - xv.z, dw = qv.w - xv.w;
    float s = dx * dx + dy * dy + dz * dz + dw * dw;

#pragma unroll
    for (int off = 32; off >= 1; off >>= 1) s += __shfl_down(s, off);
    __shared__ float red[4];
    int wave = threadIdx.x >> 6, lane = threadIdx.x & 63;
    if (lane == 0) red[wave] = s;
    __syncthreads();
    if (threadIdx.x == 0)
        partials[blockIdx.x] = (red[0] + red[1]) + (red[2] + red[3]);
}

__global__ __launch_bounds__(1024) void k_final(const float* __restrict__ partials,
                                                const int* __restrict__ counts,
                                                float* __restrict__ out_scalars) {
    int tid = threadIdx.x;
    float s = 0.f;
    for (int i = tid; i < 4096; i += 1024) s += partials[i];
#pragma unroll
    for (int off = 32; off >= 1; off >>= 1) s += __shfl_down(s, off);
    __shared__ float wsum[16];
    int wave = tid >> 6, lane = tid & 63;
    if (lane == 0) wsum[wave] = s;

    float c = (float)counts[tid];
    float p = c * (1.0f / 65536.0f);
    float t = -p * logf(p + 1e-10f);
#pragma unroll
    for (int off = 32; off >= 1; off >>= 1) t += __shfl_down(t, off);
    __shared__ float esum[16];
    if (lane == 0) esum[wave] = t;
    __syncthreads();

    if (tid == 0) {
        float total = 0.f, ent = 0.f;
        for (int w = 0; w < 16; ++w) { total += wsum[w]; ent += esum[w]; }
        float mean = total * (1.0f / (float)TOTAL_ELEMS);
        out_scalars[0] = expf(ent);
        out_scalars[1] = mean;
        out_scalars[2] = 0.25f * mean;
    }
}

extern "C" void kernel_launch(void* const* d_in, const int* in_sizes, int n_in,
                              void* d_out, int out_size, void* d_ws, size_t ws_size,
                              hipStream_t stream) {
    const float* x  = (const float*)d_in[0];
    const float* cb = (const float*)d_in[1];
    float* out = (float*)d_out;
    float* ws  = (float*)d_ws;

    float* norms    = ws;
    int*   idx      = (int*)(ws + 1024);
    int*   counts   = (int*)(ws + 66560);
    float* partials = ws + 67584;
    float* cbT      = ws + 71680;
    unsigned short* cb_hi = (unsigned short*)(ws + 137216);
    unsigned short* cb_lo = (unsigned short*)(ws + 169984);
    int*   flagcnt  = (int*)(ws + 202752);
    int*   flaglist = (int*)(ws + 202753);

    float* ste     = out;
    float* scalars = out + TOTAL_ELEMS;
    float* idxf    = out + TOTAL_ELEMS + 3;

    k_prep  <<<16,    64, 0, stream>>>(cb, norms, counts, cbT, cb_hi, cb_lo, flagcnt);
    k_assign<<<1024, 256, 0, stream>>>(x, norms, cb_hi, cb_lo, idx, flagcnt, flaglist);
    k_exact <<<1024, 256, 0, stream>>>(x, cb, norms, flagcnt, flaglist, idx);
    k_quant <<<4096, 256, 0, stream>>>(x, cbT, idx, ste, partials, counts, idxf);
    k_final <<<1,   1024, 0, stream>>>(partials, counts, scalars);
}